// Round 4
// baseline (92.411 us; speedup 1.0000x reference)
//
#include <hip/hip_runtime.h>
#include <hip/hip_bf16.h>

// NT-Xent (SimCLR) loss, B=4096, D=256, N=8192, T=0.5.
// loss = [ sum_i log(sum_{j!=i} exp(sim_ij * 2)) - 4 * sum_{i<B} pos_i ] / N
// sim symmetric: upper-triangle 128x128 tiles only (2080 of 4096). Each tile
// emits row-sums for BOTH its row-range (DPP lane reduce -> colacc) and its
// col-range (per-lane reg reduce). Double-buffered K-chunk staging (T3
// 2-phase): stage(ch+1) issued right after the barrier, latency hidden under
// compute(ch). 3 dispatches; no device fences.

constexpr int BB = 4096;                 // batch
constexpr int NN = 8192;                 // 2*batch
constexpr int DD = 256;                  // feature dim
constexpr int TS = 128;                  // tile edge
constexpr int NT = NN / TS;              // 64 tile rows/cols
constexpr int NBLK = NT * (NT + 1) / 2;  // 2080 = 8*260
constexpr int KCH = 32;                  // k-chunk (halfs): panel 8 KB
constexpr int NCH = DD / KCH;            // 8 chunks

typedef _Float16 half4v __attribute__((ext_vector_type(4)));
typedef _Float16 half8v __attribute__((ext_vector_type(8)));
typedef float floatx16 __attribute__((ext_vector_type(16)));

// ---------------- Kernel 1: normalize rows -> f16, pos partials, zero rowsum -
__global__ __launch_bounds__(256) void nt_normalize(
    const float* __restrict__ zi, const float* __restrict__ zj,
    _Float16* __restrict__ Z, float* __restrict__ posPartial,
    float* __restrict__ rowsum)
{
    const int lane = threadIdx.x & 63;
    const int wave = threadIdx.x >> 6;
    const int i = blockIdx.x * 4 + wave;   // pair index, < BB

    if (blockIdx.x < 32) rowsum[blockIdx.x * 256 + threadIdx.x] = 0.f;

    const float4 a = ((const float4*)(zi + (size_t)i * DD))[lane];
    const float4 b = ((const float4*)(zj + (size_t)i * DD))[lane];

    float ssi = a.x*a.x + a.y*a.y + a.z*a.z + a.w*a.w;
    float ssj = b.x*b.x + b.y*b.y + b.z*b.z + b.w*b.w;
    float dd  = a.x*b.x + a.y*b.y + a.z*b.z + a.w*b.w;
#pragma unroll
    for (int off = 32; off > 0; off >>= 1) {
        ssi += __shfl_xor(ssi, off);
        ssj += __shfl_xor(ssj, off);
        dd  += __shfl_xor(dd,  off);
    }
    const float invi = rsqrtf(ssi);
    const float invj = rsqrtf(ssj);

    half4v ha, hb;
    ha.x = (_Float16)(a.x * invi); ha.y = (_Float16)(a.y * invi);
    ha.z = (_Float16)(a.z * invi); ha.w = (_Float16)(a.w * invi);
    hb.x = (_Float16)(b.x * invj); hb.y = (_Float16)(b.y * invj);
    hb.z = (_Float16)(b.z * invj); hb.w = (_Float16)(b.w * invj);

    ((half4v*)(Z + (size_t)i * DD))[lane]        = ha;
    ((half4v*)(Z + (size_t)(BB + i) * DD))[lane] = hb;

    __shared__ float ps[4];
    if (lane == 0) ps[wave] = dd * invi * invj;
    __syncthreads();
    if (threadIdx.x == 0)
        posPartial[blockIdx.x] = ps[0] + ps[1] + ps[2] + ps[3];
}

// DPP half-wave reduce: lane31 = sum(lanes 0..31), lane63 = sum(lanes 32..63).
__device__ __forceinline__ float half_sums(float x) {
    int t;
    t = __builtin_amdgcn_update_dpp(0, __builtin_bit_cast(int, x), 0x111, 0xf, 0xf, false);
    x += __builtin_bit_cast(float, t);
    t = __builtin_amdgcn_update_dpp(0, __builtin_bit_cast(int, x), 0x112, 0xf, 0xf, false);
    x += __builtin_bit_cast(float, t);
    t = __builtin_amdgcn_update_dpp(0, __builtin_bit_cast(int, x), 0x114, 0xf, 0xf, false);
    x += __builtin_bit_cast(float, t);
    t = __builtin_amdgcn_update_dpp(0, __builtin_bit_cast(int, x), 0x118, 0xf, 0xf, false);
    x += __builtin_bit_cast(float, t);
    t = __builtin_amdgcn_update_dpp(0, __builtin_bit_cast(int, x), 0x142, 0xa, 0xf, false);
    x += __builtin_bit_cast(float, t);
    return x;
}

// ---------------- Kernel 2: upper-tri sim-GEMM + exp + row/col sums ----------
// Grid: 2080 blocks x 256 thr (4 waves). Block (rt,ct): 128x128 tile.
// Wave (wr,wc) computes a 64x64 quadrant: 2x2 32x32 MFMA tiles (64 acc VGPR).
// K chunked by 32, DOUBLE-BUFFERED: stage(ch+1) issued after the barrier,
// __syncthreads' implicit vmcnt(0) at iter ch+1 is exactly the arrival wait.
// LDS 32.5 KB -> 4 blocks/CU.
__global__ __launch_bounds__(256, 4) void nt_simexp(
    const _Float16* __restrict__ Z, float* __restrict__ rowsum)
{
    __shared__ _Float16 sAB[2][2][TS * KCH];   // [buf][A/B][128*32] = 32 KB
    __shared__ float colacc[TS];               // 512 B

    // Bijective XCD swizzle (2080 % 8 == 0).
    const int bid = (blockIdx.x & 7) * (NBLK / 8) + (blockIdx.x >> 3);

    // Closed-form reverse-triangular map: t counts from the bottom row.
    const int t = NBLK - 1 - bid;
    int m = (int)((sqrtf((float)(8 * t + 1)) - 1.0f) * 0.5f);
    while ((m + 1) * (m + 2) / 2 <= t) ++m;   // fixup (+-1 from sqrt rounding)
    while (m * (m + 1) / 2 > t) --m;
    const int rt = NT - 1 - m;
    const int ct = NT - 1 - (t - m * (m + 1) / 2);
    const bool diag = (rt == ct);

    const int tid = threadIdx.x;
    const int wave = tid >> 6;
    const int lane = tid & 63;
    const int lm = lane & 31;
    const int lh = lane >> 5;
    const int wr = wave >> 1;           // row half (A side)
    const int wc = wave & 1;            // col half (B side)

    const int rbase = rt * TS;          // A-side rows (output rows)
    const int cbase = ct * TS;          // B-side rows (output cols)

    if (tid < TS) colacc[tid] = 0.f;

    // Staging: per panel-chunk (128 rows x 64 B) -> 8 wave-wide DMA calls of
    // 1 KB (16 rows x 4 granules). Lane i of call c covers row 16c+(i>>2),
    // LDS granule i&3 (linear dest). Source granule pre-swizzled so that
    // LDS[r][g] holds SRC granule g ^ ((r>>1)&3)  (bank-balanced reads).
    const int st_row = lane >> 2;                     // 0..15
    const int st_sg  = (lane & 3) ^ ((lane >> 3) & 3);
    const _Float16* Ap = Z + (size_t)rbase * DD;
    const _Float16* Bp = Z + (size_t)cbase * DD;

    auto stage = [&](int buf, int ch) {
#pragma unroll
        for (int j = 0; j < 2; ++j) {
            const int c = wave + 4 * j;               // calls 0..7
            const int r = 16 * c + st_row;
            const _Float16* gA = Ap + (size_t)r * DD + ch * KCH + st_sg * 8;
            __builtin_amdgcn_global_load_lds(
                (const __attribute__((address_space(1))) unsigned int*)gA,
                (__attribute__((address_space(3))) unsigned int*)(&sAB[buf][0][c * 512]),
                16, 0, 0);
            const _Float16* gB = Bp + (size_t)r * DD + ch * KCH + st_sg * 8;
            __builtin_amdgcn_global_load_lds(
                (const __attribute__((address_space(1))) unsigned int*)gB,
                (__attribute__((address_space(3))) unsigned int*)(&sAB[buf][1][c * 512]),
                16, 0, 0);
        }
    };

    floatx16 a00, a01, a10, a11;
#pragma unroll
    for (int r = 0; r < 16; ++r) { a00[r] = 0.f; a01[r] = 0.f; a10[r] = 0.f; a11[r] = 0.f; }

    stage(0, 0);

    for (int ch = 0; ch < NCH; ++ch) {
        __syncthreads();   // implicit vmcnt(0): chunk ch arrived; all waves
                           // finished reading buf[(ch+1)&1] (their compute ch-1)
        if (ch + 1 < NCH) stage((ch + 1) & 1, ch + 1);

        const int b = ch & 1;
        __builtin_amdgcn_s_setprio(1);
#pragma unroll
        for (int s = 0; s < 2; ++s) {
            const int pg  = 2 * s + lh;                    // logical granule
            const int ph8 = (pg ^ ((lm >> 1) & 3)) * 8;    // phys offset (halfs)
            half8v fa0 = *(const half8v*)&sAB[b][0][(wr * 64 +      lm) * KCH + ph8];
            half8v fa1 = *(const half8v*)&sAB[b][0][(wr * 64 + 32 + lm) * KCH + ph8];
            half8v fb0 = *(const half8v*)&sAB[b][1][(wc * 64 +      lm) * KCH + ph8];
            half8v fb1 = *(const half8v*)&sAB[b][1][(wc * 64 + 32 + lm) * KCH + ph8];
            a00 = __builtin_amdgcn_mfma_f32_32x32x16_f16(fa0, fb0, a00, 0, 0, 0);
            a01 = __builtin_amdgcn_mfma_f32_32x32x16_f16(fa0, fb1, a01, 0, 0, 0);
            a10 = __builtin_amdgcn_mfma_f32_32x32x16_f16(fa1, fb0, a10, 0, 0, 0);
            a11 = __builtin_amdgcn_mfma_f32_32x32x16_f16(fa1, fb1, a11, 0, 0, 0);
        }
        __builtin_amdgcn_s_setprio(0);
    }

    // Epilogue: e = exp2(sim * 2*log2e). Per-lane reg sums -> col-range rows
    // (B side, index lm); DPP across lm -> row-range rows (A side, index mrow).
    const float KEXP = 2.0f * 1.44269504088896340736f;
    float eb0 = 0.f, eb1 = 0.f;
#pragma unroll
    for (int tr = 0; tr < 2; ++tr) {
#pragma unroll
        for (int r = 0; r < 16; ++r) {
            const int mrow = (r & 3) + 8 * (r >> 2) + 4 * lh;
            float e0 = __builtin_amdgcn_exp2f((tr ? a10[r] : a00[r]) * KEXP);
            float e1 = __builtin_amdgcn_exp2f((tr ? a11[r] : a01[r]) * KEXP);
            // Diagonal element: global row == col -> wr==wc, tr==tc, mrow==lm.
            // e0 carries tc=0 (zero when tr==0), e1 carries tc=1 (when tr==1).
            if (diag && (wr == wc) && (mrow == lm)) {
                if (tr == 0) e0 = 0.f; else e1 = 0.f;
            }
            eb0 += e0; eb1 += e1;
            if (!diag) {
                float s2 = half_sums(e0 + e1);   // lanes 31/63 hold half-sums
                if (lm == 31)
                    atomicAdd(&colacc[wr * 64 + tr * 32 + mrow], s2);  // ds_add
            }
        }
    }

    eb0 += __shfl_xor(eb0, 32);
    eb1 += __shfl_xor(eb1, 32);
    if (lane < 32) {
        atomicAdd(&rowsum[cbase + wc * 64 + lm], eb0);
        atomicAdd(&rowsum[cbase + wc * 64 + 32 + lm], eb1);
    }
    if (!diag) {
        __syncthreads();
        if (tid < TS) atomicAdd(&rowsum[rbase + tid], colacc[tid]);
    }
}

// ---------------- Kernel 3: finalize ----------------------------------------
__global__ __launch_bounds__(256) void nt_finalize(
    const float* __restrict__ rowsum, const float* __restrict__ posPartial,
    float* __restrict__ out)
{
    const int tid = threadIdx.x;
    float acc = 0.f;
#pragma unroll
    for (int it = 0; it < NN / 256; ++it)
        acc += __builtin_amdgcn_logf(rowsum[tid + it * 256]);   // log2
    float pacc = 0.f;
#pragma unroll
    for (int it = 0; it < 4; ++it)
        pacc += posPartial[tid + it * 256];

#pragma unroll
    for (int off = 32; off > 0; off >>= 1) {
        acc  += __shfl_xor(acc,  off);
        pacc += __shfl_xor(pacc, off);
    }
    __shared__ float sa[4], sp[4];
    const int wave = tid >> 6;
    if ((tid & 63) == 0) { sa[wave] = acc; sp[wave] = pacc; }
    __syncthreads();
    if (tid == 0) {
        const float lntot = (sa[0] + sa[1] + sa[2] + sa[3]) * 0.6931471805599453f;
        const float ptot  = sp[0] + sp[1] + sp[2] + sp[3];
        out[0] = (lntot - 4.0f * ptot) * (1.0f / (float)NN);
    }
}

// ---------------- Launch ------------------------------------------------------
extern "C" void kernel_launch(void* const* d_in, const int* in_sizes, int n_in,
                              void* d_out, int out_size, void* d_ws, size_t ws_size,
                              hipStream_t stream) {
    const float* zi = (const float*)d_in[0];
    const float* zj = (const float*)d_in[1];
    float* out = (float*)d_out;

    _Float16* Z = (_Float16*)d_ws;                                  // 4 MB
    float* rowsum = (float*)((char*)d_ws + (size_t)NN * DD * 2);    // 32 KB
    float* posPartial = rowsum + NN;                                // 4 KB

    nt_normalize<<<BB / 4, 256, 0, stream>>>(zi, zj, Z, posPartial, rowsum);
    nt_simexp<<<NBLK, 256, 0, stream>>>((const _Float16*)Z, rowsum);
    nt_finalize<<<1, 256, 0, stream>>>(rowsum, posPartial, out);
}